// Round 12
// baseline (60.488 us; speedup 1.0000x reference)
//
#include <hip/hip_runtime.h>
#include <hip/hip_bf16.h>

#define BB 4096
#define DD 512
#define LLAB 20
#define NN 8192
#define KK 64

constexpr float kNegInf = -1.0e9f;
constexpr float kLn2 = 0.69314718055994530942f;
constexpr float kWlPe = 2.5f;   // per_ex safety band (scale-branch)
constexpr float kWlTie = 2.0f;  // accuracy near-tie band
constexpr double kFix = 1073741824.0;  // 2^30 fixed-point scale

// workspace layout (bytes)
#define OFF_PEREX 0
#define OFF_STATS 16384                 // u32[8]: [0]=acc
#define OFF_MINPE (16384 + 256)         // u32[64] banked min-pe bits
#define OFF_SUMP  (16384 + 512)         // u64[64] banked sum(pe)
#define OFF_SUMS  (16384 + 1024)        // u64[64] banked sum(pe*scale)
#define OFF_SP    36864
#define OFF_SIE   53248
#define OFF_SLE   69632
#define OFF_SALE  86016
#define OFF_HLAB  118784
#define OFF_HAL   151552
#define OFF_IEQ   217088
#define OFF_LEQ   (OFF_IEQ + (size_t)BB * DD)
#define OFF_ALEQ  (OFF_LEQ + (size_t)BB * DD)
#define WS_NEED   (OFF_ALEQ + (size_t)NN * DD)

typedef unsigned u32x4 __attribute__((ext_vector_type(4)));

// Forced-prefetch 16B global load (asm keeps dest live until drained).
#define GLD(dst, base, OFFSTR)                                        \
  asm volatile("global_load_dwordx4 %0, %1, off offset:" OFFSTR      \
               : "=v"(dst) : "v"(base) : "memory")

// Counted waits + scheduling fence (rule #18).
#define VWAIT8 do { asm volatile("s_waitcnt vmcnt(8)" ::: "memory"); \
                    __builtin_amdgcn_sched_barrier(0); } while (0)
#define VWAIT0 do { asm volatile("s_waitcnt vmcnt(0)" ::: "memory"); \
                    __builtin_amdgcn_sched_barrier(0); } while (0)

// Raw barrier: LDS-visibility only, does NOT drain vmcnt (keeps prefetch).
#define LBAR do { __builtin_amdgcn_sched_barrier(0);                  \
                  asm volatile("s_waitcnt lgkmcnt(0)" ::: "memory");  \
                  __builtin_amdgcn_s_barrier();                       \
                  __builtin_amdgcn_sched_barrier(0); } while (0)

__device__ __forceinline__ float dot4(const float4& a, const float4& b) {
  return a.x * b.x + a.y * b.y + a.z * b.z + a.w * b.w;
}

__device__ __forceinline__ float waveReduceSum(float v) {
#pragma unroll
  for (int s = 1; s < 64; s <<= 1) v += __shfl_xor(v, s);
  return v;
}

__device__ __forceinline__ float waveReduceMax(float v) {
#pragma unroll
  for (int s = 1; s < 64; s <<= 1) v = fmaxf(v, __shfl_xor(v, s));
  return v;
}

__device__ __forceinline__ float waveReduceMin(float v) {
#pragma unroll
  for (int s = 1; s < 64; s <<= 1) v = fminf(v, __shfl_xor(v, s));
  return v;
}

__device__ __forceinline__ unsigned long long hash20(const float* __restrict__ p) {
  unsigned long long h = 1469598103934665603ull;
#pragma unroll
  for (int t = 0; t < LLAB; ++t) {
    h ^= (unsigned long long)__float_as_uint(p[t]);
    h *= 1099511628211ull;
  }
  return h;
}

__device__ __forceinline__ int sdot4i(unsigned a, unsigned b, int acc) {
#if __has_builtin(__builtin_amdgcn_sdot4)
  return __builtin_amdgcn_sdot4((int)a, (int)b, acc, false);
#else
#pragma unroll
  for (int t = 0; t < 4; ++t)
    acc += (int)(signed char)(a >> (8 * t)) * (int)(signed char)(b >> (8 * t));
  return acc;
#endif
}

__device__ __forceinline__ unsigned pk4i8(float a, float b, float c, float d, float inv) {
  const int q0 = (int)rintf(a * inv);
  const int q1 = (int)rintf(b * inv);
  const int q2 = (int)rintf(c * inv);
  const int q3 = (int)rintf(d * inv);
  return (q0 & 255) | ((q1 & 255) << 8) | ((q2 & 255) << 16) | ((q3 & 255) << 24);
}

__device__ __forceinline__ float max8abs(const float4& a, const float4& c) {
  return fmaxf(fmaxf(fmaxf(fabsf(a.x), fabsf(a.y)), fmaxf(fabsf(a.z), fabsf(a.w))),
               fmaxf(fmaxf(fabsf(c.x), fabsf(c.y)), fmaxf(fabsf(c.z), fabsf(c.w))));
}

__device__ __forceinline__ float loss_scale(float pe) {
  const float q = expf(-pe);
  const float t = 2.0f * (1.0f - q);
  const float t2 = t * t;
  return t2 * t2;
}

__device__ __forceinline__ void accum_loss(int b, float pe, unsigned* minpeB,
                                           unsigned long long* sumP,
                                           unsigned long long* sumS) {
  const float pc = fmaxf(pe, 0.0f);
  const int bank = b & 63;
  atomicMin(&minpeB[bank], __float_as_uint(pc));
  atomicAdd(&sumP[bank], (unsigned long long)((double)pc * kFix + 0.5));
  atomicAdd(&sumS[bank],
            (unsigned long long)((double)(pc * loss_scale(pc)) * kFix + 0.5));
}

__global__ void init_kernel(unsigned* stats) {
  if (threadIdx.x == 0) stats[0] = 0u;
}

// Prep (one wave per row): quantize ie+le (w<BB) with exact sim_pos, or ale;
// hash label tables; init stats/banks.
__global__ __launch_bounds__(256) void prep_kernel(
    const float* __restrict__ ie, const float* __restrict__ le,
    const float* __restrict__ ale, const float* __restrict__ labels,
    const float* __restrict__ al, char* __restrict__ ie_q,
    char* __restrict__ le_q, char* __restrict__ ale_q,
    float* __restrict__ s_ie, float* __restrict__ s_le,
    float* __restrict__ s_ale, float* __restrict__ sp,
    unsigned long long* __restrict__ h_lab,
    unsigned long long* __restrict__ h_al, unsigned* __restrict__ stats,
    unsigned* __restrict__ minpeB, unsigned long long* __restrict__ sumP,
    unsigned long long* __restrict__ sumS) {
  const int tid = threadIdx.x;
  const int lane = tid & 63;
  const int wave = tid >> 6;
  const int w = blockIdx.x * 4 + wave;

  if (w < BB) {
    const float4* i4 = (const float4*)(ie + (size_t)w * DD);
    const float4* l4 = (const float4*)(le + (size_t)w * DD);
    const float4 a0 = i4[2 * lane], a1 = i4[2 * lane + 1];
    const float4 b0 = l4[2 * lane], b1 = l4[2 * lane + 1];
    float p = dot4(a0, b0) + dot4(a1, b1);
    p = waveReduceSum(p);
    float mi = fmaxf(waveReduceMax(max8abs(a0, a1)), 1e-20f);
    const float inv_i = 127.0f / mi;
    uint2 oi;
    oi.x = pk4i8(a0.x, a0.y, a0.z, a0.w, inv_i);
    oi.y = pk4i8(a1.x, a1.y, a1.z, a1.w, inv_i);
    ((uint2*)(ie_q + (size_t)w * DD))[lane] = oi;
    float ml = fmaxf(waveReduceMax(max8abs(b0, b1)), 1e-20f);
    const float inv_l = 127.0f / ml;
    uint2 ol;
    ol.x = pk4i8(b0.x, b0.y, b0.z, b0.w, inv_l);
    ol.y = pk4i8(b1.x, b1.y, b1.z, b1.w, inv_l);
    ((uint2*)(le_q + (size_t)w * DD))[lane] = ol;
    if (lane == 0) {
      sp[w] = p;
      s_ie[w] = mi * (1.0f / 127.0f);
      s_le[w] = ml * (1.0f / 127.0f);
    }
  } else {
    const int row = w - BB;
    const float4* r4 = (const float4*)(ale + (size_t)row * DD);
    const float4 a = r4[2 * lane], c = r4[2 * lane + 1];
    float mx = fmaxf(waveReduceMax(max8abs(a, c)), 1e-20f);
    const float inv = 127.0f / mx;
    uint2 o;
    o.x = pk4i8(a.x, a.y, a.z, a.w, inv);
    o.y = pk4i8(c.x, c.y, c.z, c.w, inv);
    ((uint2*)(ale_q + (size_t)row * DD))[lane] = o;
    if (lane == 0) s_ale[row] = mx * (1.0f / 127.0f);
  }

  const int g = blockIdx.x * 256 + tid;
  if (g < 2) stats[g] = 0u;
  if (g < 64) {
    minpeB[g] = 0x7F800000u;  // +inf
    sumP[g] = 0ull;
    sumS[g] = 0ull;
  }
  if (g < BB) h_lab[g] = hash20(labels + (size_t)g * LLAB);
  else if (g < BB + NN) h_al[g - BB] = hash20(al + (size_t)(g - BB) * LLAB);
}

// Exact f32 row compute (fallback + in-kernel fixup path).
__device__ __forceinline__ void row_f32_body(
    int b, const float* __restrict__ ie, const float* __restrict__ le,
    const float* __restrict__ labels, const float* __restrict__ ale,
    const float* __restrict__ al, const int* __restrict__ nin,
    const int* __restrict__ nlb, float* __restrict__ per_ex,
    unsigned* __restrict__ stats, bool count_acc, float* sims, float* wred) {
  const int tid = threadIdx.x;
  const int lane = tid & 63;
  const int wave = tid >> 6;

  const float4* ie4 = (const float4*)(ie + (size_t)b * DD);
  const float4* le4 = (const float4*)(le + (size_t)b * DD);
  float4 ier0 = ie4[lane], ier1 = ie4[lane + 64];
  float4 ler0 = le4[lane], ler1 = le4[lane + 64];
  float lab = (lane < LLAB) ? labels[(size_t)b * LLAB + lane] : 0.0f;

  if (wave == 0) {
    float p = dot4(ier0, ler0) + dot4(ier1, ler1);
    p = waveReduceSum(p);
    if (lane == 0) sims[0] = p;
  }

#pragma unroll 2
  for (int kk = 0; kk < KK / 4; ++kk) {
    const int k = wave * (KK / 4) + kk;
    const int j_lb = __builtin_amdgcn_readfirstlane(nlb[(size_t)b * KK + k]);
    const int j_in = __builtin_amdgcn_readfirstlane(nin[(size_t)b * KK + k]);

    const float4* rle = (const float4*)(ale + (size_t)j_lb * DD);
    const float4* rie = (const float4*)(ie + (size_t)j_in * DD);
    float4 vle0 = rle[lane], vle1 = rle[lane + 64];
    float4 vie0 = rie[lane], vie1 = rie[lane + 64];

    bool ein = true, elb = true;
    if (lane < LLAB) {
      ein = (labels[(size_t)j_in * LLAB + lane] == lab);
      elb = (al[(size_t)j_lb * LLAB + lane] == lab);
    }
    const bool bad_in = (__ballot(ein) == ~0ull);
    const bool bad_lb = (__ballot(elb) == ~0ull);

    float a_il = dot4(vle0, ier0) + dot4(vle1, ier1);
    float a_ll = dot4(vle0, ler0) + dot4(vle1, ler1);
    float a_ii = dot4(vie0, ier0) + dot4(vie1, ier1);
    float a_li = dot4(vie0, ler0) + dot4(vie1, ler1);

    const bool oddl = (lane & 1) != 0;
    float sx = oddl ? a_il : a_ii;
    float sy = oddl ? a_ll : a_li;
    float rx = __shfl_xor(sx, 1);
    float ry = __shfl_xor(sy, 1);
    float mx = (oddl ? a_ii : a_il) + rx;
    float my = (oddl ? a_li : a_ll) + ry;
    const bool hi2 = (lane & 2) != 0;
    float s1 = hi2 ? mx : my;
    float r1 = __shfl_xor(s1, 2);
    float v = (hi2 ? my : mx) + r1;
    v += __shfl_xor(v, 4);
    v += __shfl_xor(v, 8);
    v += __shfl_xor(v, 16);
    v += __shfl_xor(v, 32);

    if (lane < 4) {
      const bool badf = (lane & 1) ? bad_in : bad_lb;
      const float s = badf ? v + kNegInf : v;
      const int slot = ((lane & 1) << 1) | ((lane >> 1) & 1);
      sims[1 + slot * KK + k] = s;
    }
  }
  __syncthreads();

  const float v = sims[1 + tid];
  const float s0 = sims[0];
  float wmax = waveReduceMax(v);
  if (lane == 0) wred[wave] = wmax;
  __syncthreads();
  float m = fmaxf(fmaxf(wred[0], wred[1]), fmaxf(wred[2], wred[3]));
  m = fmaxf(m, s0);
  const float e = expf(v - m);
  float wsum = waveReduceSum(e);
  if (lane == 0) wred[4 + wave] = wsum;
  __syncthreads();
  if (tid == 0) {
    const float tot = wred[4] + wred[5] + wred[6] + wred[7] + expf(s0 - m);
    per_ex[b] = m + logf(tot) - s0;
    if (count_acc) {
      const float max_il = wred[0];
      if (s0 >= max_il) atomicAdd(&stats[0], 1u);
    }
  }
}

// Main pass: 1024 blocks x 4 rows each. Octet-per-k (8 lanes per negative),
// half-row phases of 8 GLDs/lane, double-buffered sets A/B with counted
// vmcnt(8) — issue never stops, including across rows (raw s_barrier keeps
// prefetch in flight through the LSE).
__global__ __launch_bounds__(256) void row_i8_kernel(
    const float* __restrict__ ie, const float* __restrict__ le,
    const float* __restrict__ labels, const float* __restrict__ ale,
    const float* __restrict__ al, const char* __restrict__ ie_q,
    const char* __restrict__ le_q, const char* __restrict__ ale_q,
    const float* __restrict__ s_ie, const float* __restrict__ s_le,
    const float* __restrict__ s_ale, const float* __restrict__ sp,
    const unsigned long long* __restrict__ h_lab,
    const unsigned long long* __restrict__ h_al,
    const int* __restrict__ nin, const int* __restrict__ nlb,
    float* __restrict__ per_ex, unsigned* __restrict__ stats,
    unsigned* __restrict__ minpeB, unsigned long long* __restrict__ sumP,
    unsigned long long* __restrict__ sumS) {
  const int b0 = blockIdx.x * 4;
  const int tid = threadIdx.x;
  const int lane = tid & 63;
  const int wave = tid >> 6;
  const int o = lane & 7;     // lane within octet
  const int oct = lane >> 3;  // octet within wave

  __shared__ u32x4 qls[256];      // [row][qi|ql][32 chunks], 4 KB
  __shared__ int jls[256], jis[256];
  __shared__ float sAs[256], sBs[256];  // sign bit = bad-negative flag
  __shared__ float sims[1 + 4 * KK];
  __shared__ float wred[8];
  __shared__ int do_fix;

  // ---- block start: stage everything the hot loop needs (all VMEM here) ----
  {
    const int r = wave;            // wave r stages row b0+r
    const int br = b0 + r;
    const u32x4* qsrc = (lane < 32)
        ? ((const u32x4*)(ie_q + ((size_t)br << 9))) + lane
        : ((const u32x4*)(le_q + ((size_t)br << 9))) + (lane - 32);
    qls[r * 64 + lane] = *qsrc;

    const int k = tid & 63;        // thread covers (r, k)
    const int jl = nlb[br * KK + k];
    const int ji = nin[br * KK + k];
    const unsigned long long hbr = h_lab[br];
    const bool blb = (h_al[jl] == hbr);
    const bool bin = (h_lab[ji] == hbr);
    const float sa = s_ale[jl];
    const float sb = s_ie[ji];
    jls[tid] = jl;
    jis[tid] = ji;
    sAs[tid] = blb ? -sa : sa;
    sBs[tid] = bin ? -sb : sb;
  }
  float sp_r[4], sqi_r[4], sql_r[4];
#pragma unroll
  for (int rr = 0; rr < 4; ++rr) {
    sp_r[rr] = sp[b0 + rr];
    sqi_r[rr] = s_ie[b0 + rr];
    sql_r[rr] = s_le[b0 + rr];
  }
  __syncthreads();  // full barrier once; drains all staging loads

  u32x4 A0, A1, A2, A3, A4, A5, A6, A7;
  u32x4 B0, B1, B2, B3, B4, B5, B6, B7;

#define ISSUE8(S, rr, hh)                                                 \
  {                                                                       \
    const int k_ = (hh) * 32 + (wave << 3) + oct;                         \
    const int jl_ = jls[(rr) * 64 + k_];                                  \
    const int ji_ = jis[(rr) * 64 + k_];                                  \
    const char* pa_ = ale_q + ((size_t)jl_ << 9) + (o << 4);              \
    const char* pb_ = ie_q + ((size_t)ji_ << 9) + (o << 4);               \
    GLD(S##0, pa_, "0");   GLD(S##1, pa_, "128");                         \
    GLD(S##2, pa_, "256"); GLD(S##3, pa_, "384");                         \
    GLD(S##4, pb_, "0");   GLD(S##5, pb_, "128");                         \
    GLD(S##6, pb_, "256"); GLD(S##7, pb_, "384");                         \
  }

#define COMPUTE8(S, rr, hh)                                               \
  {                                                                       \
    const u32x4 a0_ = S##0, a1_ = S##1, a2_ = S##2, a3_ = S##3;           \
    const u32x4 e0_ = S##4, e1_ = S##5, e2_ = S##6, e3_ = S##7;           \
    const int k_ = (hh) * 32 + (wave << 3) + oct;                         \
    const u32x4 q0 = qls[(rr) * 64 + o];                                  \
    const u32x4 q1 = qls[(rr) * 64 + o + 8];                              \
    const u32x4 q2 = qls[(rr) * 64 + o + 16];                             \
    const u32x4 q3 = qls[(rr) * 64 + o + 24];                             \
    const u32x4 l0 = qls[(rr) * 64 + 32 + o];                             \
    const u32x4 l1 = qls[(rr) * 64 + 32 + o + 8];                         \
    const u32x4 l2 = qls[(rr) * 64 + 32 + o + 16];                        \
    const u32x4 l3 = qls[(rr) * 64 + 32 + o + 24];                        \
    int il = 0, ll = 0, ii = 0, li = 0;                                   \
    il = sdot4i(a0_.x, q0.x, il); il = sdot4i(a0_.y, q0.y, il);           \
    il = sdot4i(a0_.z, q0.z, il); il = sdot4i(a0_.w, q0.w, il);           \
    il = sdot4i(a1_.x, q1.x, il); il = sdot4i(a1_.y, q1.y, il);           \
    il = sdot4i(a1_.z, q1.z, il); il = sdot4i(a1_.w, q1.w, il);           \
    il = sdot4i(a2_.x, q2.x, il); il = sdot4i(a2_.y, q2.y, il);           \
    il = sdot4i(a2_.z, q2.z, il); il = sdot4i(a2_.w, q2.w, il);           \
    il = sdot4i(a3_.x, q3.x, il); il = sdot4i(a3_.y, q3.y, il);           \
    il = sdot4i(a3_.z, q3.z, il); il = sdot4i(a3_.w, q3.w, il);           \
    ll = sdot4i(a0_.x, l0.x, ll); ll = sdot4i(a0_.y, l0.y, ll);           \
    ll = sdot4i(a0_.z, l0.z, ll); ll = sdot4i(a0_.w, l0.w, ll);           \
    ll = sdot4i(a1_.x, l1.x, ll); ll = sdot4i(a1_.y, l1.y, ll);           \
    ll = sdot4i(a1_.z, l1.z, ll); ll = sdot4i(a1_.w, l1.w, ll);           \
    ll = sdot4i(a2_.x, l2.x, ll); ll = sdot4i(a2_.y, l2.y, ll);           \
    ll = sdot4i(a2_.z, l2.z, ll); ll = sdot4i(a2_.w, l2.w, ll);           \
    ll = sdot4i(a3_.x, l3.x, ll); ll = sdot4i(a3_.y, l3.y, ll);           \
    ll = sdot4i(a3_.z, l3.z, ll); ll = sdot4i(a3_.w, l3.w, ll);           \
    ii = sdot4i(e0_.x, q0.x, ii); ii = sdot4i(e0_.y, q0.y, ii);           \
    ii = sdot4i(e0_.z, q0.z, ii); ii = sdot4i(e0_.w, q0.w, ii);           \
    ii = sdot4i(e1_.x, q1.x, ii); ii = sdot4i(e1_.y, q1.y, ii);           \
    ii = sdot4i(e1_.z, q1.z, ii); ii = sdot4i(e1_.w, q1.w, ii);           \
    ii = sdot4i(e2_.x, q2.x, ii); ii = sdot4i(e2_.y, q2.y, ii);           \
    ii = sdot4i(e2_.z, q2.z, ii); ii = sdot4i(e2_.w, q2.w, ii);           \
    ii = sdot4i(e3_.x, q3.x, ii); ii = sdot4i(e3_.y, q3.y, ii);           \
    ii = sdot4i(e3_.z, q3.z, ii); ii = sdot4i(e3_.w, q3.w, ii);           \
    li = sdot4i(e0_.x, l0.x, li); li = sdot4i(e0_.y, l0.y, li);           \
    li = sdot4i(e0_.z, l0.z, li); li = sdot4i(e0_.w, l0.w, li);           \
    li = sdot4i(e1_.x, l1.x, li); li = sdot4i(e1_.y, l1.y, li);           \
    li = sdot4i(e1_.z, l1.z, li); li = sdot4i(e1_.w, l1.w, li);           \
    li = sdot4i(e2_.x, l2.x, li); li = sdot4i(e2_.y, l2.y, li);           \
    li = sdot4i(e2_.z, l2.z, li); li = sdot4i(e2_.w, l2.w, li);           \
    li = sdot4i(e3_.x, l3.x, li); li = sdot4i(e3_.y, l3.y, li);           \
    li = sdot4i(e3_.z, l3.z, li); li = sdot4i(e3_.w, l3.w, li);           \
    const bool odd = (lane & 1) != 0;                                     \
    const int x_ = odd ? il : ii;                                         \
    const int y_ = odd ? ll : li;                                         \
    const int rx_ = __shfl_xor(x_, 1);                                    \
    const int ry_ = __shfl_xor(y_, 1);                                    \
    const int aa_ = (odd ? ii : il) + rx_;                                \
    const int bb_ = (odd ? li : ll) + ry_;                                \
    const bool hi2_ = (lane & 2) != 0;                                    \
    const int s1_ = hi2_ ? aa_ : bb_;                                     \
    const int r1_ = __shfl_xor(s1_, 2);                                   \
    int vi_ = (hi2_ ? bb_ : aa_) + r1_;                                   \
    vi_ += __shfl_xor(vi_, 4);                                            \
    if ((lane & 4) == 0) {                                                \
      const int c_ = lane & 3;                                            \
      const float scq = (c_ & 1) ? sBs[(rr) * 64 + k_]                    \
                                 : sAs[(rr) * 64 + k_];                   \
      const float sq_ = (c_ & 2) ? sql_r[rr] : sqi_r[rr];                 \
      float v_ = (float)vi_ * (fabsf(scq) * sq_);                         \
      if (scq < 0.0f) v_ += kNegInf;                                      \
      const int slot_ = ((c_ & 1) << 1) | (c_ >> 1);                      \
      sims[1 + slot_ * KK + k_] = v_;                                     \
    }                                                                     \
  }

#define LSE(rr)                                                           \
  {                                                                       \
    LBAR;                                                                 \
    const float vv = sims[1 + tid];                                       \
    const float s0 = sp_r[rr];                                            \
    float wmax = waveReduceMax(vv);                                       \
    if (lane == 0) wred[wave] = wmax;                                     \
    LBAR;                                                                 \
    float m = fmaxf(fmaxf(wred[0], wred[1]), fmaxf(wred[2], wred[3]));    \
    m = fmaxf(m, s0);                                                     \
    const float e = expf(vv - m);                                         \
    float wsum = waveReduceSum(e);                                        \
    if (lane == 0) wred[4 + wave] = wsum;                                 \
    LBAR;                                                                 \
    if (tid == 0) {                                                       \
      const float tot = wred[4] + wred[5] + wred[6] + wred[7] +           \
                        expf(s0 - m);                                     \
      const float pe = m + logf(tot) - s0;                                \
      per_ex[b0 + (rr)] = pe;                                             \
      const float max_il = wred[0];                                       \
      const bool wl_row = (pe < kWlPe) || (fabsf(s0 - max_il) < kWlTie);  \
      do_fix = wl_row ? 1 : 0;                                            \
      if (!wl_row) {                                                      \
        if (s0 >= max_il) atomicAdd(&stats[0], 1u);                       \
        accum_loss(b0 + (rr), pe, minpeB, sumP, sumS);                    \
      }                                                                   \
    }                                                                     \
    LBAR;                                                                 \
    if (do_fix) {                                                         \
      row_f32_body(b0 + (rr), ie, le, labels, ale, al, nin, nlb,          \
                   per_ex, stats, true, sims, wred);                      \
      if (tid == 0) accum_loss(b0 + (rr), per_ex[b0 + (rr)],              \
                               minpeB, sumP, sumS);                       \
      __syncthreads();                                                    \
    }                                                                     \
  }

  // ---- pipelined phase schedule: 8 half-row phases, sets alternate ----
  ISSUE8(A, 0, 0);
  ISSUE8(B, 0, 1); VWAIT8; COMPUTE8(A, 0, 0);
  ISSUE8(A, 1, 0); VWAIT8; COMPUTE8(B, 0, 1); LSE(0);
  ISSUE8(B, 1, 1); VWAIT8; COMPUTE8(A, 1, 0);
  ISSUE8(A, 2, 0); VWAIT8; COMPUTE8(B, 1, 1); LSE(1);
  ISSUE8(B, 2, 1); VWAIT8; COMPUTE8(A, 2, 0);
  ISSUE8(A, 3, 0); VWAIT8; COMPUTE8(B, 2, 1); LSE(2);
  ISSUE8(B, 3, 1); VWAIT8; COMPUTE8(A, 3, 0);
                   VWAIT0; COMPUTE8(B, 3, 1); LSE(3);

#undef ISSUE8
#undef COMPUTE8
#undef LSE
}

// Fallback: full exact pass (used only if ws too small).
__global__ __launch_bounds__(256) void row_f32_kernel(
    const float* __restrict__ ie, const float* __restrict__ le,
    const float* __restrict__ labels, const float* __restrict__ ale,
    const float* __restrict__ al, const int* __restrict__ nin,
    const int* __restrict__ nlb, float* __restrict__ per_ex,
    unsigned* __restrict__ stats) {
  __shared__ float sims[1 + 4 * KK];
  __shared__ float wred[8];
  row_f32_body(blockIdx.x, ie, le, labels, ale, al, nin, nlb, per_ex, stats,
               true, sims, wred);
}

// Tiny finalize: 1 wave reduces the 64 banks.
__global__ __launch_bounds__(64) void finalize2_kernel(
    const unsigned* __restrict__ stats, const unsigned* __restrict__ minpeB,
    const unsigned long long* __restrict__ sumP,
    const unsigned long long* __restrict__ sumS, float* __restrict__ out) {
  const int lane = threadIdx.x;
  unsigned mb = minpeB[lane];
  unsigned long long p = sumP[lane];
  unsigned long long q = sumS[lane];
#pragma unroll
  for (int s = 1; s < 64; s <<= 1) {
    mb = min(mb, (unsigned)__shfl_xor((int)mb, s));
    p += (unsigned long long)__shfl_xor((long long)p, s);
    q += (unsigned long long)__shfl_xor((long long)q, s);
  }
  if (lane == 0) {
    const float minpe = __uint_as_float(mb);
    const bool scale_on = (minpe < kLn2);  // max(q) > 0.5
    const double tot = (double)(scale_on ? q : p) / kFix;
    out[0] = (float)(tot / (double)BB);
    out[1] = (float)stats[0] / (float)BB;
  }
}

// Fallback finalize (per_ex based).
__global__ __launch_bounds__(256) void finalize_kernel(
    const float* __restrict__ per_ex, const unsigned* __restrict__ stats,
    float* __restrict__ out) {
  __shared__ float pe_s[BB];
  __shared__ float wred[8];
  const int tid = threadIdx.x;
  const int lane = tid & 63;
  const int wave = tid >> 6;

  float mn = 1.0e30f;
#pragma unroll 4
  for (int i = tid; i < BB; i += 256) {
    const float v = per_ex[i];
    pe_s[i] = v;
    mn = fminf(mn, v);
  }
  mn = waveReduceMin(mn);
  if (lane == 0) wred[wave] = mn;
  __syncthreads();
  const float minpe = fminf(fminf(wred[0], wred[1]), fminf(wred[2], wred[3]));
  const bool scale_on = (minpe < kLn2);
  __syncthreads();

  float sum = 0.0f;
#pragma unroll 4
  for (int i = tid; i < BB; i += 256) {
    const float pe = pe_s[i];
    sum += pe * (scale_on ? loss_scale(pe) : 1.0f);
  }
  sum = waveReduceSum(sum);
  if (lane == 0) wred[4 + wave] = sum;
  __syncthreads();
  if (tid == 0) {
    const float tot = wred[4] + wred[5] + wred[6] + wred[7];
    out[0] = tot / (float)BB;
    out[1] = (float)stats[0] / (float)BB;
  }
}

extern "C" void kernel_launch(void* const* d_in, const int* in_sizes, int n_in,
                              void* d_out, int out_size, void* d_ws, size_t ws_size,
                              hipStream_t stream) {
  const float* ie = (const float*)d_in[0];
  const float* le = (const float*)d_in[1];
  const float* labels = (const float*)d_in[2];
  const float* ale = (const float*)d_in[3];
  const float* al = (const float*)d_in[4];
  const int* nin = (const int*)d_in[5];
  const int* nlb = (const int*)d_in[6];
  float* out = (float*)d_out;

  float* per_ex = (float*)d_ws;
  unsigned* stats = (unsigned*)((char*)d_ws + OFF_STATS);

  if (ws_size >= WS_NEED) {
    char* ie_q = (char*)d_ws + OFF_IEQ;
    char* le_q = (char*)d_ws + OFF_LEQ;
    char* ale_q = (char*)d_ws + OFF_ALEQ;
    float* s_ie = (float*)((char*)d_ws + OFF_SIE);
    float* s_le = (float*)((char*)d_ws + OFF_SLE);
    float* s_ale = (float*)((char*)d_ws + OFF_SALE);
    float* sp = (float*)((char*)d_ws + OFF_SP);
    unsigned long long* h_lab = (unsigned long long*)((char*)d_ws + OFF_HLAB);
    unsigned long long* h_al = (unsigned long long*)((char*)d_ws + OFF_HAL);
    unsigned* minpeB = (unsigned*)((char*)d_ws + OFF_MINPE);
    unsigned long long* sumP = (unsigned long long*)((char*)d_ws + OFF_SUMP);
    unsigned long long* sumS = (unsigned long long*)((char*)d_ws + OFF_SUMS);

    const int prep_blocks = (BB + NN) / 4;
    hipLaunchKernelGGL(prep_kernel, dim3(prep_blocks), dim3(256), 0, stream,
                       ie, le, ale, labels, al, ie_q, le_q, ale_q,
                       s_ie, s_le, s_ale, sp, h_lab, h_al, stats,
                       minpeB, sumP, sumS);
    hipLaunchKernelGGL(row_i8_kernel, dim3(BB / 4), dim3(256), 0, stream,
                       ie, le, labels, ale, al, ie_q, le_q, ale_q,
                       s_ie, s_le, s_ale, sp, h_lab, h_al, nin, nlb,
                       per_ex, stats, minpeB, sumP, sumS);
    hipLaunchKernelGGL(finalize2_kernel, dim3(1), dim3(64), 0, stream,
                       stats, minpeB, sumP, sumS, out);
  } else {
    hipLaunchKernelGGL(init_kernel, dim3(1), dim3(64), 0, stream, stats);
    hipLaunchKernelGGL(row_f32_kernel, dim3(BB), dim3(256), 0, stream,
                       ie, le, labels, ale, al, nin, nlb, per_ex, stats);
    hipLaunchKernelGGL(finalize_kernel, dim3(1), dim3(256), 0, stream,
                       per_ex, stats, out);
  }
}